// Round 1
// baseline (1700.466 us; speedup 1.0000x reference)
//
#include <hip/hip_runtime.h>

#define HH 32
#define LOG2E 1.44269504088896340736f
#define KCH 16   // TF pipeline chunk length (steps per ring half)

typedef float v2f __attribute__((ext_vector_type(2)));

// DPP: quad_perm broadcasts (gate q = lane&3) and row rotates (16-lane rows)
#define DPPF(v, ctrl) \
    __int_as_float(__builtin_amdgcn_update_dpp(0, __float_as_int(v), (ctrl), 0xF, 0xF, true))
#define QP_B0 0x00   // [0,0,0,0] -> gate i to all quad lanes
#define QP_B1 0x55   // [1,1,1,1] -> gate f
#define QP_B2 0xAA   // [2,2,2,2] -> gate g
#define QP_B3 0xFF   // [3,3,3,3] -> gate o
#define DPP_ROR4  0x124
#define DPP_ROR8  0x128
#define SWZ(v, pat) __int_as_float(__builtin_amdgcn_ds_swizzle(__float_as_int(v), (pat)))

__device__ __forceinline__ float hw_exp2(float x) {
    float r; asm("v_exp_f32 %0, %1" : "=v"(r) : "v"(x)); return r;
}
__device__ __forceinline__ float sigm_e(float z, float e) {
    return __builtin_amdgcn_rcpf(1.0f + hw_exp2(z * e));
}
__device__ __forceinline__ v2f pk_fma(v2f a, v2f b, v2f c) {
    return __builtin_elementwise_fma(a, b, c);   // v_pk_fma_f32
}
__device__ __forceinline__ void load_bc(const float* p, v2f* d) {
#pragma unroll
    for (int r = 0; r < 8; ++r) {                // 8x ds_read_b128 broadcast
        float4 v = ((const float4*)p)[r];
        d[2*r]   = (v2f){v.x, v.y};
        d[2*r+1] = (v2f){v.z, v.w};
    }
}
// sum over 16 channel-groups (used in TF only; off AR critical path now)
__device__ __forceinline__ float out_reduce(float p) {
    p += DPPF(p, DPP_ROR4);
    p += DPPF(p, DPP_ROR8);
    p += SWZ(p, 0x401F);             // xor16
    p += __shfl_xor(p, 32, 64);      // halves
    return p;
}

// 2-row (A,B) dot over 16 v2f weight regs; ACC=false starts with pk_mul (no zero-init)
template<bool ACC>
__device__ __forceinline__ void dot2(const v2f* hv, const v2f* mA, const v2f* mB,
                                     v2f& P0, v2f& P1, v2f& P2, v2f& P3) {
    if (ACC) {
        P0 = pk_fma(hv[0], mA[0], P0); P1 = pk_fma(hv[1], mA[1], P1);
        P2 = pk_fma(hv[0], mB[0], P2); P3 = pk_fma(hv[1], mB[1], P3);
    } else {
        P0 = hv[0] * mA[0]; P1 = hv[1] * mA[1];
        P2 = hv[0] * mB[0]; P3 = hv[1] * mB[1];
    }
#pragma unroll
    for (int r = 2; r < 16; r += 2) {
        P0 = pk_fma(hv[r],   mA[r],   P0);
        P1 = pk_fma(hv[r+1], mA[r+1], P1);
        P2 = pk_fma(hv[r],   mB[r],   P2);
        P3 = pk_fma(hv[r+1], mB[r+1], P3);
    }
}

__device__ __forceinline__ void gate_hc(float zA, float zB, float es, float mm, float cc,
                                        float& cA, float& cB, float& hA, float& hB) {
    float acA = fmaf(mm, sigm_e(zA, es), cc);
    float acB = fmaf(mm, sigm_e(zB, es), cc);
    float iA = DPPF(acA, QP_B0), fA = DPPF(acA, QP_B1);
    float gA = DPPF(acA, QP_B2), oA = DPPF(acA, QP_B3);
    float iB = DPPF(acB, QP_B0), fB = DPPF(acB, QP_B1);
    float gB = DPPF(acB, QP_B2), oB = DPPF(acB, QP_B3);
    cA = fmaf(fA, cA, iA * gA);
    cB = fmaf(fB, cB, iB * gB);
    hA = oA * fmaf(2.0f, sigm_e(cA, -2.0f * LOG2E), -1.0f);
    hB = oB * fmaf(2.0f, sigm_e(cB, -2.0f * LOG2E), -1.0f);
}

// Block = 256 threads = 4 waves = 2 wave-pairs; each pair owns 2 batch elems.
// Within a pair: role w=0 -> cell1, role w=1 -> cell2(+TF outputs).
// Lane layout unchanged: q=lane&3 (gate), ch=lane>>2; rows (q<<5)|ch, (q<<5)|(ch+16).
__global__ __launch_bounds__(256, 1)
void lstm_seq_kernel(const float* __restrict__ input,
                     const float* __restrict__ W_ih1, const float* __restrict__ W_hh1,
                     const float* __restrict__ b_ih1, const float* __restrict__ b_hh1,
                     const float* __restrict__ W_ih2, const float* __restrict__ W_hh2,
                     const float* __restrict__ b_ih2, const float* __restrict__ b_hh2,
                     const float* __restrict__ W_lin, const float* __restrict__ b_lin,
                     float* __restrict__ out, int T, int total)
{
    const int tid  = threadIdx.x;
    const int wave = tid >> 6;
    const int lane = tid & 63;
    const int pair = wave >> 1;      // 0,1
    const int w    = wave & 1;       // role
    const int q    = lane & 3;
    const int ch   = lane >> 2;
    const int rowA = (q << 5) | ch;
    const int rowB = (q << 5) | (ch + 16);

    const int e0i = blockIdx.x + (pair << 9);   // + pair*512
    const int e1i = e0i + 256;

    __shared__ __align__(16) float ring[2][2][KCH][2][HH]; // [pair][half][slot][elem][ch]
    __shared__ __align__(16) float h1x[2][2][HH];          // [pair][elem]
    __shared__ __align__(16) float h2s[2][2][HH];

    float* ring_p = &ring[pair][0][0][0][0];
    float* h1x0 = &h1x[pair][0][0]; float* h1x1 = &h1x[pair][1][0];
    float* h2s0 = &h2s[pair][0][0]; float* h2s1 = &h2s[pair][1][0];

    const bool  isg = (q == 2);
    const float es  = isg ? (-2.0f * LOG2E) : (-LOG2E);
    const float mm  = isg ? 2.0f : 1.0f;
    const float cc  = isg ? -1.0f : 0.0f;

    // per-role weights. w0: m1=Whh1, m2A=Wlin broadcast (AR out-dot).
    // w1: m1=Wih2, m2=Whh2.
    v2f m1A[16], m1B[16], m2A[16], m2B[16];
    float wxA = 0.f, wxB = 0.f, bA, bB, wlA = 0.f, wlB = 0.f, blin;
    if (w == 0) {
        const v2f* pA = (const v2f*)(W_hh1 + rowA * HH);
        const v2f* pB = (const v2f*)(W_hh1 + rowB * HH);
        const v2f* wp = (const v2f*)W_lin;
#pragma unroll
        for (int r = 0; r < 16; ++r) { m1A[r] = pA[r]; m1B[r] = pB[r]; m2A[r] = wp[r]; }
        wxA = W_ih1[rowA]; wxB = W_ih1[rowB];
        bA  = b_ih1[rowA] + b_hh1[rowA];
        bB  = b_ih1[rowB] + b_hh1[rowB];
    } else {
        const v2f* pA = (const v2f*)(W_ih2 + rowA * HH);
        const v2f* pB = (const v2f*)(W_ih2 + rowB * HH);
        const v2f* qA = (const v2f*)(W_hh2 + rowA * HH);
        const v2f* qB = (const v2f*)(W_hh2 + rowB * HH);
#pragma unroll
        for (int r = 0; r < 16; ++r) { m1A[r] = pA[r]; m1B[r] = pB[r];
                                       m2A[r] = qA[r]; m2B[r] = qB[r]; }
        bA  = b_ih2[rowA] + b_hh2[rowA];
        bB  = b_ih2[rowB] + b_hh2[rowB];
        wlA = W_lin[ch]; wlB = W_lin[ch + 16];
    }
    blin = b_lin[0];

    // per-elem states (role-local meaning: w0 -> c1 / Whh1-dot, w1 -> c2 / Whh2-dot)
    float cA0 = 0.f, cB0 = 0.f, cA1 = 0.f, cB1 = 0.f;
    v2f p00 = {0.f,0.f}, p01 = {0.f,0.f}, p02 = {0.f,0.f}, p03 = {0.f,0.f};
    v2f p10 = {0.f,0.f}, p11 = {0.f,0.f}, p12 = {0.f,0.f}, p13 = {0.f,0.f};

    const float* __restrict__ inp0  = input + (size_t)e0i * T;
    const float* __restrict__ inp1  = input + (size_t)e1i * T;
    float* __restrict__       outp0 = out   + (size_t)e0i * total;
    float* __restrict__       outp1 = out   + (size_t)e1i * total;

    // ============== Teacher-forced phase: chunk pipeline, 2 elems/wave ==============
    if (w == 0) {
        int t = 0;
        float x0 = inp0[0], x1 = inp1[0];
        for (int cb = 0; t < T; ++cb) {
            float* buf = ring_p + (cb & 1) * (KCH * 2 * HH);
            int S = T - t; if (S > KCH) S = KCH;
            for (int s = 0; s < S; ++s, ++t) {
                float xa = x0, xb = x1;
                int tn = t + 1; int tc = tn < T ? tn : 0;
                x0 = inp0[tc]; x1 = inp1[tc];              // prefetch, off-path
                float z1A0 = fmaf(xa, wxA, bA + (p00.x+p00.y) + (p01.x+p01.y));
                float z1B0 = fmaf(xa, wxB, bB + (p02.x+p02.y) + (p03.x+p03.y));
                float z1A1 = fmaf(xb, wxA, bA + (p10.x+p10.y) + (p11.x+p11.y));
                float z1B1 = fmaf(xb, wxB, bB + (p12.x+p12.y) + (p13.x+p13.y));
                float hA0, hB0, hA1, hB1;
                gate_hc(z1A0, z1B0, es, mm, cc, cA0, cB0, hA0, hB0);
                gate_hc(z1A1, z1B1, es, mm, cc, cA1, cB1, hA1, hB1);
                float* slot = buf + s * (2 * HH);
                if (q == 0) { slot[ch] = hA0;      slot[ch + 16] = hB0;
                              slot[HH + ch] = hA1; slot[HH + ch + 16] = hB1; }
                v2f hv0[16], hv1[16];
                load_bc(slot, hv0); load_bc(slot + HH, hv1);   // same-wave round trip
                dot2<false>(hv0, m1A, m1B, p00, p01, p02, p03);
                dot2<false>(hv1, m1A, m1B, p10, p11, p12, p13);
            }
            __syncthreads();          // chunk published
        }
        __syncthreads();              // match consumer
    } else {
        __syncthreads();              // wait for chunk 0
        int t = 0;
        for (int cb = 0; t < T; ++cb) {
            const float* buf = ring_p + (cb & 1) * (KCH * 2 * HH);
            int S = T - t; if (S > KCH) S = KCH;
            for (int s = 0; s < S; ++s, ++t) {
                const float* slot = buf + s * (2 * HH);
                v2f hv0[16], hv1[16];
                load_bc(slot, hv0); load_bc(slot + HH, hv1);
                v2f s00 = p00, s01 = p01, s02 = p02, s03 = p03;
                v2f s10 = p10, s11 = p11, s12 = p12, s13 = p13;
                dot2<true>(hv0, m1A, m1B, s00, s01, s02, s03);
                dot2<true>(hv1, m1A, m1B, s10, s11, s12, s13);
                float z2A0 = bA + (s00.x+s00.y) + (s01.x+s01.y);
                float z2B0 = bB + (s02.x+s02.y) + (s03.x+s03.y);
                float z2A1 = bA + (s10.x+s10.y) + (s11.x+s11.y);
                float z2B1 = bB + (s12.x+s12.y) + (s13.x+s13.y);
                float hA0, hB0, hA1, hB1;
                gate_hc(z2A0, z2B0, es, mm, cc, cA0, cB0, hA0, hB0);
                gate_hc(z2A1, z2B1, es, mm, cc, cA1, cB1, hA1, hB1);
                if (q == 0) { h2s0[ch] = hA0; h2s0[ch + 16] = hB0;
                              h2s1[ch] = hA1; h2s1[ch + 16] = hB1; }
                v2f gv0[16], gv1[16];
                load_bc(h2s0, gv0); load_bc(h2s1, gv1);        // same-wave round trip
                dot2<false>(gv0, m2A, m2B, p00, p01, p02, p03);
                dot2<false>(gv1, m2A, m2B, p10, p11, p12, p13);
                float pr0 = fmaf(hA0, wlA, hB0 * wlB);
                float pr1 = fmaf(hA1, wlA, hB1 * wlB);
                float o0 = out_reduce(pr0) + blin;
                float o1 = out_reduce(pr1) + blin;
                if (lane == 0) { outp0[t] = o0; outp1[t] = o1; }
            }
            __syncthreads();
        }
    }

    // ============== Autoregressive phase: staggered pipeline, 1 barrier/cell ========
    // slot A: w0 cell1(e0), w1 cell2(e1);  slot B: w0 cell1(e1), w1 cell2(e0).
    // w0 recomputes x = Wlin.h2 + blin per-lane from broadcast h2 (m2A holds Wlin).
    const int fut = total - T;
    for (int sp = 0; sp <= fut; ++sp) {
        // ---------- slot A ----------
        __syncthreads();
        if (w == 0) {
            v2f gv[16]; load_bc(h2s0, gv);
            v2f oa = gv[0] * m2A[0], ob = gv[1] * m2A[1];
#pragma unroll
            for (int r = 2; r < 16; r += 2) { oa = pk_fma(gv[r], m2A[r], oa);
                                              ob = pk_fma(gv[r+1], m2A[r+1], ob); }
            float xo = (oa.x + oa.y) + (ob.x + ob.y) + blin;
            if (sp >= 1 && lane == 0) outp0[T - 1 + sp] = xo;
            if (sp < fut) {
                float z1A = fmaf(xo, wxA, bA + (p00.x+p00.y) + (p01.x+p01.y));
                float z1B = fmaf(xo, wxB, bB + (p02.x+p02.y) + (p03.x+p03.y));
                float hA, hB;
                gate_hc(z1A, z1B, es, mm, cc, cA0, cB0, hA, hB);
                if (q == 0) { h1x0[ch] = hA; h1x0[ch + 16] = hB; }
                v2f hv[16]; load_bc(h1x0, hv);                 // own write, shadow dot
                dot2<false>(hv, m1A, m1B, p00, p01, p02, p03);
            }
        } else if (sp >= 1) {                                  // cell2 elem1
            v2f hv[16]; load_bc(h1x1, hv);
            v2f s0 = p10, s1 = p11, s2 = p12, s3 = p13;
            dot2<true>(hv, m1A, m1B, s0, s1, s2, s3);
            float z2A = bA + (s0.x+s0.y) + (s1.x+s1.y);
            float z2B = bB + (s2.x+s2.y) + (s3.x+s3.y);
            float hA, hB;
            gate_hc(z2A, z2B, es, mm, cc, cA1, cB1, hA, hB);
            if (q == 0) { h2s1[ch] = hA; h2s1[ch + 16] = hB; }
            v2f gv[16]; load_bc(h2s1, gv);
            dot2<false>(gv, m2A, m2B, p10, p11, p12, p13);
        }
        // ---------- slot B ----------
        __syncthreads();
        if (w == 0) {
            v2f gv[16]; load_bc(h2s1, gv);
            v2f oa = gv[0] * m2A[0], ob = gv[1] * m2A[1];
#pragma unroll
            for (int r = 2; r < 16; r += 2) { oa = pk_fma(gv[r], m2A[r], oa);
                                              ob = pk_fma(gv[r+1], m2A[r+1], ob); }
            float xo = (oa.x + oa.y) + (ob.x + ob.y) + blin;
            if (sp >= 1 && lane == 0) outp1[T - 1 + sp] = xo;
            if (sp < fut) {
                float z1A = fmaf(xo, wxA, bA + (p10.x+p10.y) + (p11.x+p11.y));
                float z1B = fmaf(xo, wxB, bB + (p12.x+p12.y) + (p13.x+p13.y));
                float hA, hB;
                gate_hc(z1A, z1B, es, mm, cc, cA1, cB1, hA, hB);
                if (q == 0) { h1x1[ch] = hA; h1x1[ch + 16] = hB; }
                v2f hv[16]; load_bc(h1x1, hv);
                dot2<false>(hv, m1A, m1B, p10, p11, p12, p13);
            }
        } else if (sp < fut) {                                 // cell2 elem0
            v2f hv[16]; load_bc(h1x0, hv);
            v2f s0 = p00, s1 = p01, s2 = p02, s3 = p03;
            dot2<true>(hv, m1A, m1B, s0, s1, s2, s3);
            float z2A = bA + (s0.x+s0.y) + (s1.x+s1.y);
            float z2B = bB + (s2.x+s2.y) + (s3.x+s3.y);
            float hA, hB;
            gate_hc(z2A, z2B, es, mm, cc, cA0, cB0, hA, hB);
            if (q == 0) { h2s0[ch] = hA; h2s0[ch + 16] = hB; }
            v2f gv[16]; load_bc(h2s0, gv);
            dot2<false>(gv, m2A, m2B, p00, p01, p02, p03);
        }
    }
}

extern "C" void kernel_launch(void* const* d_in, const int* in_sizes, int n_in,
                              void* d_out, int out_size, void* d_ws, size_t ws_size,
                              hipStream_t stream) {
    const int B = 1024;                 // fixed by the source module
    const int T = in_sizes[0] / B;      // 999
    const int total = out_size / B;     // T + future = 1999

    lstm_seq_kernel<<<dim3(B / 4), dim3(256), 0, stream>>>(
        (const float*)d_in[0],
        (const float*)d_in[1], (const float*)d_in[2],
        (const float*)d_in[3], (const float*)d_in[4],
        (const float*)d_in[5], (const float*)d_in[6],
        (const float*)d_in[7], (const float*)d_in[8],
        (const float*)d_in[9], (const float*)d_in[10],
        (float*)d_out, T, total);
}

// Round 2
// 1204.570 us; speedup vs baseline: 1.4117x; 1.4117x over previous
//
#include <hip/hip_runtime.h>

#define HH 32
#define LOG2E 1.44269504088896340736f
#define KCH 16   // TF pipeline chunk length (steps per ring half)

typedef float v2f __attribute__((ext_vector_type(2)));

// DPP: quad_perm broadcasts (gate q = lane&3) and row rotates (16-lane rows)
#define DPPF(v, ctrl) \
    __int_as_float(__builtin_amdgcn_update_dpp(0, __float_as_int(v), (ctrl), 0xF, 0xF, true))
#define QP_B0 0x00   // [0,0,0,0] -> gate i to all quad lanes
#define QP_B1 0x55   // [1,1,1,1] -> gate f
#define QP_B2 0xAA   // [2,2,2,2] -> gate g
#define QP_B3 0xFF   // [3,3,3,3] -> gate o
#define DPP_ROR4  0x124
#define DPP_ROR8  0x128
#define SWZ(v, pat) __int_as_float(__builtin_amdgcn_ds_swizzle(__float_as_int(v), (pat)))

__device__ __forceinline__ float hw_exp2(float x) {
    float r; asm("v_exp_f32 %0, %1" : "=v"(r) : "v"(x)); return r;
}
__device__ __forceinline__ float sigm_e(float z, float e) {
    return __builtin_amdgcn_rcpf(1.0f + hw_exp2(z * e));
}
__device__ __forceinline__ v2f pk_fma(v2f a, v2f b, v2f c) {
    return __builtin_elementwise_fma(a, b, c);   // v_pk_fma_f32
}
__device__ __forceinline__ void load_bc(const float* p, v2f* d) {
#pragma unroll
    for (int r = 0; r < 8; ++r) {                // 8x ds_read_b128 broadcast
        float4 v = ((const float4*)p)[r];
        d[2*r]   = (v2f){v.x, v.y};
        d[2*r+1] = (v2f){v.z, v.w};
    }
}
// sum over 16 channel-groups: TF outputs only (off the AR critical path now)
__device__ __forceinline__ float out_reduce(float p) {
    p += DPPF(p, DPP_ROR4);          // + ch rotated by 1 within row
    p += DPPF(p, DPP_ROR8);          // each lane = sum of its row's 4 ch
    p += SWZ(p, 0x401F);             // xor16: row pairs within 32-group
    p += __shfl_xor(p, 32, 64);      // combine halves
    return p;
}

// 2-row (A,B) dot over 16 v2f weight regs; ACC=false starts with pk_mul (no zero-init)
template<bool ACC>
__device__ __forceinline__ void dot2(const v2f* hv, const v2f* mA, const v2f* mB,
                                     v2f& P0, v2f& P1, v2f& P2, v2f& P3) {
    if (ACC) {
        P0 = pk_fma(hv[0], mA[0], P0); P1 = pk_fma(hv[1], mA[1], P1);
        P2 = pk_fma(hv[0], mB[0], P2); P3 = pk_fma(hv[1], mB[1], P3);
    } else {
        P0 = hv[0] * mA[0]; P1 = hv[1] * mA[1];
        P2 = hv[0] * mB[0]; P3 = hv[1] * mB[1];
    }
#pragma unroll
    for (int r = 2; r < 16; r += 2) {
        P0 = pk_fma(hv[r],   mA[r],   P0);
        P1 = pk_fma(hv[r+1], mA[r+1], P1);
        P2 = pk_fma(hv[r],   mB[r],   P2);
        P3 = pk_fma(hv[r+1], mB[r+1], P3);
    }
}

__device__ __forceinline__ void gate_hc(float zA, float zB, float es, float mm, float cc,
                                        float& cA, float& cB, float& hA, float& hB) {
    float acA = fmaf(mm, sigm_e(zA, es), cc);
    float acB = fmaf(mm, sigm_e(zB, es), cc);
    float iA = DPPF(acA, QP_B0), fA = DPPF(acA, QP_B1);
    float gA = DPPF(acA, QP_B2), oA = DPPF(acA, QP_B3);
    float iB = DPPF(acB, QP_B0), fB = DPPF(acB, QP_B1);
    float gB = DPPF(acB, QP_B2), oB = DPPF(acB, QP_B3);
    cA = fmaf(fA, cA, iA * gA);
    cB = fmaf(fB, cB, iB * gB);
    hA = oA * fmaf(2.0f, sigm_e(cA, -2.0f * LOG2E), -1.0f);
    hB = oB * fmaf(2.0f, sigm_e(cB, -2.0f * LOG2E), -1.0f);
}

// Layout (both waves): q=lane&3 (gate 0=i 1=f 2=g 3=o), ch=lane>>2 (0..15).
// Lane owns rows rowA=(q<<5)|ch and rowB=(q<<5)|(ch+16).
// 1024 blocks x 128 threads = 2048 waves = 2/SIMD co-residency (the latency hider).
__global__ __launch_bounds__(128, 2)
void lstm_seq_kernel(const float* __restrict__ input,
                     const float* __restrict__ W_ih1, const float* __restrict__ W_hh1,
                     const float* __restrict__ b_ih1, const float* __restrict__ b_hh1,
                     const float* __restrict__ W_ih2, const float* __restrict__ W_hh2,
                     const float* __restrict__ b_ih2, const float* __restrict__ b_hh2,
                     const float* __restrict__ W_lin, const float* __restrict__ b_lin,
                     float* __restrict__ out, int T, int total)
{
    const int b    = blockIdx.x;     // one block (2 waves) per batch element
    const int tid  = threadIdx.x;
    const int w    = tid >> 6;       // wave0 = cell1 (+AR feedback), wave1 = cell2 (+TF out)
    const int lane = tid & 63;
    const int q    = lane & 3;
    const int ch   = lane >> 2;      // 0..15
    const int rowA = (q << 5) | ch;
    const int rowB = (q << 5) | (ch + 16);

    __shared__ __align__(16) float ring[2 * KCH * HH];  // h1 stream (TF)
    __shared__ __align__(16) float h1x[HH];             // AR h1 exchange
    __shared__ __align__(16) float h2s[HH];             // h2 broadcast (w1 self + AR feedback src)

    const bool  isg = (q == 2);
    const float es  = isg ? (-2.0f * LOG2E) : (-LOG2E);
    const float mm  = isg ? 2.0f : 1.0f;
    const float cc  = isg ? -1.0f : 0.0f;

    // ---- per-wave weights ----
    // w0: m1=Whh1 rows, wl[16]=Wlin broadcast (AR per-lane feedback dot)
    // w1: m1=Wih2 rows, m2=Whh2 rows, wlA/wlB for TF out_reduce
    v2f m1A[16], m1B[16], m2A[16], m2B[16], wl[16];
    float wxA = 0.f, wxB = 0.f, bA, bB, wlA = 0.f, wlB = 0.f, blin;
    if (w == 0) {
        const v2f* pA = (const v2f*)(W_hh1 + rowA * HH);
        const v2f* pB = (const v2f*)(W_hh1 + rowB * HH);
        const v2f* wp = (const v2f*)W_lin;
#pragma unroll
        for (int r = 0; r < 16; ++r) { m1A[r] = pA[r]; m1B[r] = pB[r]; wl[r] = wp[r]; }
        wxA = W_ih1[rowA]; wxB = W_ih1[rowB];
        bA  = b_ih1[rowA] + b_hh1[rowA];
        bB  = b_ih1[rowB] + b_hh1[rowB];
    } else {
        const v2f* pA = (const v2f*)(W_ih2 + rowA * HH);
        const v2f* pB = (const v2f*)(W_ih2 + rowB * HH);
        const v2f* qA = (const v2f*)(W_hh2 + rowA * HH);
        const v2f* qB = (const v2f*)(W_hh2 + rowB * HH);
#pragma unroll
        for (int r = 0; r < 16; ++r) { m1A[r] = pA[r]; m1B[r] = pB[r];
                                       m2A[r] = qA[r]; m2B[r] = qB[r]; }
        bA  = b_ih2[rowA] + b_hh2[rowA];
        bB  = b_ih2[rowB] + b_hh2[rowB];
        wlA = W_lin[ch]; wlB = W_lin[ch + 16];
    }
    blin = b_lin[0];

    float cA = 0.f, cB = 0.f;        // c1 (wave0) / c2 (wave1), redundant on all lanes
    // carried pure dots: wave0: Whh1·h1(t-1); wave1: Whh2·h2(t-1)
    v2f p0 = {0.f,0.f}, p1 = {0.f,0.f}, p2 = {0.f,0.f}, p3 = {0.f,0.f};

    const float* __restrict__ inp  = input + (size_t)b * T;
    float* __restrict__       outp = out   + (size_t)b * total;

    // ================= Teacher-forced phase: chunk pipeline =================
    if (w == 0) {
        int t = 0;
        float xcur = inp[0];
        for (int cb = 0; t < T; ++cb) {
            float* buf = ring + (cb & 1) * (KCH * HH);
            int S = T - t; if (S > KCH) S = KCH;
            for (int s = 0; s < S; ++s, ++t) {
                float x = xcur;
                int tn = t + 1;
                xcur = inp[tn < T ? tn : 0];            // prefetch, off-path
                float z1A = fmaf(x, wxA, bA + (p0.x + p0.y) + (p1.x + p1.y));
                float z1B = fmaf(x, wxB, bB + (p2.x + p2.y) + (p3.x + p3.y));
                float hA, hB;
                gate_hc(z1A, z1B, es, mm, cc, cA, cB, hA, hB);
                float* slot = buf + s * HH;
                if (q == 0) { slot[ch] = hA; slot[ch + 16] = hB; }
                v2f hv[16]; load_bc(slot, hv);           // same-wave round trip
                dot2<false>(hv, m1A, m1B, p0, p1, p2, p3);
            }
            __syncthreads();          // chunk published
        }
        __syncthreads();              // match consumer
    } else {
        __syncthreads();              // wait for chunk 0
        int t = 0;
        for (int cb = 0; t < T; ++cb) {
            const float* buf = ring + (cb & 1) * (KCH * HH);
            int S = T - t; if (S > KCH) S = KCH;
            for (int s = 0; s < S; ++s, ++t) {
                v2f hv[16]; load_bc(buf + s * HH, hv);
                // fresh Wih2·h1 accumulated in place onto carried Whh2·h2 (p dead after z2)
                dot2<true>(hv, m1A, m1B, p0, p1, p2, p3);
                float z2A = bA + (p0.x + p0.y) + (p1.x + p1.y);
                float z2B = bB + (p2.x + p2.y) + (p3.x + p3.y);
                float hA, hB;
                gate_hc(z2A, z2B, es, mm, cc, cA, cB, hA, hB);
                if (q == 0) { h2s[ch] = hA; h2s[ch + 16] = hB; }
                v2f gv[16]; load_bc(h2s, gv);            // same-wave round trip
                dot2<false>(gv, m2A, m2B, p0, p1, p2, p3);
                float pr = fmaf(hA, wlA, hB * wlB);
                float ov = out_reduce(pr) + blin;
                if (lane == 0) outp[t] = ov;
            }
            __syncthreads();
        }
    }

    // ================= Autoregressive phase: 2 barriers/step =================
    // w0 recomputes x(t) = Wlin·h2(t-1)+b per-lane from the h2s broadcast:
    // no cross-lane reduce, no xbuf hop on the critical chain.
    for (int t = T; t < total; ++t) {
        __syncthreads();                        // BX: h2s(t-1) visible, h1x WAR safe
        if (w == 0) {
            v2f gv[16]; load_bc(h2s, gv);
            v2f oa = gv[0] * wl[0], ob = gv[1] * wl[1];
#pragma unroll
            for (int r = 2; r < 16; r += 2) { oa = pk_fma(gv[r],   wl[r],   oa);
                                              ob = pk_fma(gv[r+1], wl[r+1], ob); }
            float xo = (oa.x + oa.y) + (ob.x + ob.y) + blin;   // = out(t-1)
            if (t > T && lane == 0) outp[t - 1] = xo;          // outp[T-1] done by TF
            float z1A = fmaf(xo, wxA, bA + (p0.x + p0.y) + (p1.x + p1.y));
            float z1B = fmaf(xo, wxB, bB + (p2.x + p2.y) + (p3.x + p3.y));
            float hA, hB;
            gate_hc(z1A, z1B, es, mm, cc, cA, cB, hA, hB);
            if (q == 0) { h1x[ch] = hA; h1x[ch + 16] = hB; }
        } else {
            v2f gv[16]; load_bc(h2s, gv);       // own write from prev step
            dot2<false>(gv, m2A, m2B, p0, p1, p2, p3);   // refresh Whh2·h2 carry
        }
        __syncthreads();                        // BH: h1x visible
        if (w == 0) {
            v2f hv[16]; load_bc(h1x, hv);       // next z1 carry (shadow)
            dot2<false>(hv, m1A, m1B, p0, p1, p2, p3);
        } else {
            v2f hv[16]; load_bc(h1x, hv);
            dot2<true>(hv, m1A, m1B, p0, p1, p2, p3);    // in place: p dead after z2
            float z2A = bA + (p0.x + p0.y) + (p1.x + p1.y);
            float z2B = bB + (p2.x + p2.y) + (p3.x + p3.y);
            float hA, hB;
            gate_hc(z2A, z2B, es, mm, cc, cA, cB, hA, hB);
            if (q == 0) { h2s[ch] = hA; h2s[ch + 16] = hB; }
        }
    }
    // tail: final output out(total-1) = Wlin·h2(total-1)+b
    __syncthreads();
    if (w == 0) {
        v2f gv[16]; load_bc(h2s, gv);
        v2f oa = gv[0] * wl[0], ob = gv[1] * wl[1];
#pragma unroll
        for (int r = 2; r < 16; r += 2) { oa = pk_fma(gv[r],   wl[r],   oa);
                                          ob = pk_fma(gv[r+1], wl[r+1], ob); }
        if (lane == 0) outp[total - 1] = (oa.x + oa.y) + (ob.x + ob.y) + blin;
    }
}

extern "C" void kernel_launch(void* const* d_in, const int* in_sizes, int n_in,
                              void* d_out, int out_size, void* d_ws, size_t ws_size,
                              hipStream_t stream) {
    const int B = 1024;                 // fixed by the source module
    const int T = in_sizes[0] / B;      // 999
    const int total = out_size / B;     // T + future = 1999

    lstm_seq_kernel<<<dim3(B), dim3(128), 0, stream>>>(
        (const float*)d_in[0],
        (const float*)d_in[1], (const float*)d_in[2],
        (const float*)d_in[3], (const float*)d_in[4],
        (const float*)d_in[5], (const float*)d_in[6],
        (const float*)d_in[7], (const float*)d_in[8],
        (const float*)d_in[9], (const float*)d_in[10],
        (float*)d_out, T, total);
}